// Round 1
// baseline (169.370 us; speedup 1.0000x reference)
//
#include <hip/hip_runtime.h>
#include <hip/hip_bf16.h>

// attention_84464826843938: additive-attention pooling, MI355X (gfx950)
//
// Plan:
//  K1 pack_w_k : W_w [2048,512] fp32 -> bf16 in MFMA B-fragment order (ws, 2 MB)
//  K2 prep_p_k : p'[b,d] = prev@W2_w + W2_b[d] + W_b[d]  (ws+2MB, 512 KB)
//  K3 attn_main_k (grid 256 = 1 block/CU, 256 thr = 4 waves):
//     phase1: c-tile GEMM via mfma_f32_16x16x32_bf16, A reg-staged fp32->bf16
//             into double-buffered LDS (1 barrier/K-step), B-frags direct from
//             packed global (L2-hot, 16B/lane coalesced)
//     epi   : tanh(+p') and score = c@W3 fully in registers (c never stored),
//             16-lane shfl reduce -> per-wave partials in LDS
//     phase2: softmax over R=64 in wave 0
//     phase3: q = sum_r aw[r]*features[b,r,:] in fp32 (features re-read, L3-hot)

#define B_ 256
#define R_ 64
#define F_ 2048
#define H_ 512
#define DIM_ 512

typedef short bf16x8 __attribute__((ext_vector_type(8)));   // 8 bf16 (4 VGPRs)
typedef float f32x4 __attribute__((ext_vector_type(4)));    // MFMA acc

__device__ __forceinline__ ushort f2bf(float x) {
  __hip_bfloat16 h = __float2bfloat16(x);   // RNE
  return __builtin_bit_cast(ushort, h);
}

__device__ __forceinline__ uint4 pack8(float4 x, float4 y) {
  uint4 r;
  r.x = (uint)f2bf(x.x) | ((uint)f2bf(x.y) << 16);
  r.y = (uint)f2bf(x.z) | ((uint)f2bf(x.w) << 16);
  r.z = (uint)f2bf(y.x) | ((uint)f2bf(y.y) << 16);
  r.w = (uint)f2bf(y.z) | ((uint)f2bf(y.w) << 16);
  return r;
}

// wpack[((kt32*32 + ctg)*64 + g*16 + c)*8 + i] = bf16(W_w[kt32*32 + g*8 + i][ctg*16 + c])
// => per (kt32, ctg): one contiguous 1 KB block = exactly one wave's B-fragment.
__global__ void pack_w_k(const float* __restrict__ Ww, ushort* __restrict__ wpack) {
  int idx = blockIdx.x * 256 + threadIdx.x;       // coalesced read over [k][d]
  float v = Ww[idx];
  int k = idx >> 9;          // /DIM_
  int d = idx & 511;
  int kt = k >> 5, kr = k & 31;
  int g = kr >> 3, i = kr & 7;
  int ctg = d >> 4, c = d & 15;
  size_t dst = ((size_t)((kt * 32 + ctg) * 64 + g * 16 + c)) * 8 + (size_t)i;
  wpack[dst] = f2bf(v);
}

// p'[b][d] = sum_h prev[b][h]*W2_w[h][d] + W2_b[d] + W_b[d]
__global__ __launch_bounds__(256) void prep_p_k(const float* __restrict__ prev,
                                                const float* __restrict__ W2w,
                                                const float* __restrict__ W2b,
                                                const float* __restrict__ Wb,
                                                float* __restrict__ pprime) {
  __shared__ float lprev[8][H_];
  int bb0 = blockIdx.x * 8;       // grid = 32, 8 batch rows per block
  int t = threadIdx.x;
  const float4* src = reinterpret_cast<const float4*>(prev + (size_t)bb0 * H_);
  float4* dst = reinterpret_cast<float4*>(&lprev[0][0]);
  for (int i = t; i < 8 * H_ / 4; i += 256) dst[i] = src[i];
  __syncthreads();
  #pragma unroll
  for (int dd = 0; dd < 2; ++dd) {
    int d = t + dd * 256;
    float acc[8];
    #pragma unroll
    for (int bb = 0; bb < 8; ++bb) acc[bb] = 0.f;
    #pragma unroll 4
    for (int h = 0; h < H_; ++h) {
      float wv = W2w[h * DIM_ + d];               // coalesced; reused for 8 b's
      #pragma unroll
      for (int bb = 0; bb < 8; ++bb) acc[bb] += lprev[bb][h] * wv;  // LDS broadcast
    }
    float bias = W2b[d] + Wb[d];
    #pragma unroll
    for (int bb = 0; bb < 8; ++bb) pprime[(size_t)(bb0 + bb) * DIM_ + d] = acc[bb] + bias;
  }
}

__device__ __forceinline__ float fast_tanh(float x) {
  // tanh(x) = 1 - 2/(exp(2x)+1); hw exp saturates cleanly to +-1
  float e = __expf(2.f * x);
  return 1.f - 2.f / (e + 1.f);
}

__global__ __launch_bounds__(256, 1) void attn_main_k(const float* __restrict__ feat,
                                                      const ushort* __restrict__ wpack,
                                                      const float* __restrict__ pprime,
                                                      const float* __restrict__ W3,
                                                      float* __restrict__ out) {
  int b = blockIdx.x;
  int t = threadIdx.x;
  int wid = t >> 6;       // wave id: owns cols [wid*128, wid*128+128)
  int l = t & 63;
  int l15 = l & 15, g = l >> 4;
  const float* featB = feat + (size_t)b * R_ * F_;

  // A tile (64 rows x 64 k) in bf16 fragment-chunk order: chunk# = kc*64 + row,
  // chunk = A[row][kt*64 + kc*8 .. +8]. Reader lane l (ksub s, rowtile rt):
  // chunk = (s*4+g)*64 + rt*16 + l15  -> consecutive 16B per 16-lane group.
  __shared__ uint4 ldsA[2][512];          // 2 x 8 KB double buffer
  __shared__ float lds_part[4][R_];
  __shared__ float lds_aw[R_];

  f32x4 acc[4][8];
  #pragma unroll
  for (int rt = 0; rt < 4; ++rt)
    #pragma unroll
    for (int ct = 0; ct < 8; ++ct)
      acc[rt][ct] = (f32x4){0.f, 0.f, 0.f, 0.f};

  int row = t >> 2, kq = t & 3;           // staging: thread covers 16 floats of one row
  const float* rowp = featB + (size_t)row * F_ + kq * 16;

  { // prologue: stage K-tile 0
    const float4* src = reinterpret_cast<const float4*>(rowp);
    float4 a0 = src[0], a1 = src[1], a2 = src[2], a3 = src[3];
    ldsA[0][(kq * 2 + 0) * 64 + row] = pack8(a0, a1);
    ldsA[0][(kq * 2 + 1) * 64 + row] = pack8(a2, a3);
  }

  for (int kt = 0; kt < 32; ++kt) {       // K-step = 64
    int cur = kt & 1;
    // prefetch next A tile (global->regs, no LDS dependence -> overlaps barrier)
    float4 a0, a1, a2, a3;
    if (kt < 31) {
      const float4* src = reinterpret_cast<const float4*>(rowp + (kt + 1) * 64);
      a0 = src[0]; a1 = src[1]; a2 = src[2]; a3 = src[3];
    }
    // prefetch this step's 16 B-fragments (global, L2-hot, coalesced 1KB/wave)
    uint4 bfr[2][8];
    const ushort* wp = wpack + ((size_t)(kt * 2) * 32 + (size_t)wid * 8) * 512 + (size_t)l * 8;
    #pragma unroll
    for (int s = 0; s < 2; ++s)
      #pragma unroll
      for (int ct = 0; ct < 8; ++ct)
        bfr[s][ct] = *reinterpret_cast<const uint4*>(wp + (size_t)(s * 32 + ct) * 512);

    __syncthreads();                       // staged writes of tile kt now visible

    bf16x8 af[2][4];
    #pragma unroll
    for (int s = 0; s < 2; ++s)
      #pragma unroll
      for (int rt = 0; rt < 4; ++rt)
        af[s][rt] = __builtin_bit_cast(bf16x8, ldsA[cur][(s * 4 + g) * 64 + rt * 16 + l15]);

    #pragma unroll
    for (int s = 0; s < 2; ++s)
      #pragma unroll
      for (int ct = 0; ct < 8; ++ct) {
        bf16x8 bv = __builtin_bit_cast(bf16x8, bfr[s][ct]);
        #pragma unroll
        for (int rt = 0; rt < 4; ++rt)
          acc[rt][ct] = __builtin_amdgcn_mfma_f32_16x16x32_bf16(af[s][rt], bv, acc[rt][ct], 0, 0, 0);
      }

    if (kt < 31) {  // write next tile into the other buffer (safe: one barrier/step)
      ldsA[cur ^ 1][(kq * 2 + 0) * 64 + row] = pack8(a0, a1);
      ldsA[cur ^ 1][(kq * 2 + 1) * 64 + row] = pack8(a2, a3);
    }
  }

  // ---- epilogue: tanh + score, all in registers; c is never materialized ----
  // acc[rt][ct][j] = c[row = rt*16 + g*4 + j][col = wid*128 + ct*16 + l15]
  float pp[8], w3v[8];
  #pragma unroll
  for (int ct = 0; ct < 8; ++ct) {
    int col = wid * 128 + ct * 16 + l15;
    pp[ct] = pprime[b * DIM_ + col];
    w3v[ct] = W3[col];
  }
  #pragma unroll
  for (int rt = 0; rt < 4; ++rt) {
    #pragma unroll
    for (int j = 0; j < 4; ++j) {
      float v = 0.f;
      #pragma unroll
      for (int ct = 0; ct < 8; ++ct)
        v += fast_tanh(acc[rt][ct][j] + pp[ct]) * w3v[ct];
      v += __shfl_xor(v, 1);
      v += __shfl_xor(v, 2);
      v += __shfl_xor(v, 4);
      v += __shfl_xor(v, 8);               // 16-lane group sum -> full 128-col partial
      if (l15 == 0) lds_part[wid][rt * 16 + g * 4 + j] = v;
    }
  }
  __syncthreads();

  // ---- softmax over R=64 (wave 0; W3_b cancels in softmax) ----
  if (t < R_) {
    float s = lds_part[0][t] + lds_part[1][t] + lds_part[2][t] + lds_part[3][t];
    float m = s;
    #pragma unroll
    for (int off = 32; off >= 1; off >>= 1) m = fmaxf(m, __shfl_xor(m, off));
    float e = __expf(s - m);
    float su = e;
    #pragma unroll
    for (int off = 32; off >= 1; off >>= 1) su += __shfl_xor(su, off);
    lds_aw[t] = e / su;
  }
  __syncthreads();

  // ---- weighted sum: q[b][f] = sum_r aw[r] * features[b][r][f] (fp32) ----
  int f0 = t * 8;
  float qa[8];
  #pragma unroll
  for (int i = 0; i < 8; ++i) qa[i] = 0.f;
  const float* fp = featB + f0;
  #pragma unroll 8
  for (int r = 0; r < R_; ++r) {
    float a = lds_aw[r];
    const float4* v = reinterpret_cast<const float4*>(fp + (size_t)r * F_);
    float4 v0 = v[0], v1 = v[1];
    qa[0] += a * v0.x; qa[1] += a * v0.y; qa[2] += a * v0.z; qa[3] += a * v0.w;
    qa[4] += a * v1.x; qa[5] += a * v1.y; qa[6] += a * v1.z; qa[7] += a * v1.w;
  }
  float4* o = reinterpret_cast<float4*>(out + (size_t)b * F_ + f0);
  o[0] = (float4){qa[0], qa[1], qa[2], qa[3]};
  o[1] = (float4){qa[4], qa[5], qa[6], qa[7]};
}

extern "C" void kernel_launch(void* const* d_in, const int* in_sizes, int n_in,
                              void* d_out, int out_size, void* d_ws, size_t ws_size,
                              hipStream_t stream) {
  const float* feat = (const float*)d_in[0];   // [B,R,F]
  const float* prev = (const float*)d_in[1];   // [B,H]
  const float* Ww   = (const float*)d_in[2];   // [F,DIM]
  const float* Wb   = (const float*)d_in[3];   // [DIM]
  const float* W2w  = (const float*)d_in[4];   // [H,DIM]
  const float* W2b  = (const float*)d_in[5];   // [DIM]
  const float* W3w  = (const float*)d_in[6];   // [DIM,1]
  // d_in[7] = W3_b: constant shift, cancels in softmax
  float* out = (float*)d_out;

  ushort* wpack  = (ushort*)d_ws;                                  // 2 MB
  float*  pprime = (float*)((char*)d_ws + (size_t)F_ * DIM_ * 2);  // 512 KB

  pack_w_k<<<(F_ * DIM_) / 256, 256, 0, stream>>>(Ww, wpack);
  prep_p_k<<<B_ / 8, 256, 0, stream>>>(prev, W2w, W2b, Wb, pprime);
  attn_main_k<<<B_, 256, 0, stream>>>(feat, wpack, pprime, W3w, out);
}

// Round 2
// 123.872 us; speedup vs baseline: 1.3673x; 1.3673x over previous
//
#include <hip/hip_runtime.h>
#include <hip/hip_bf16.h>

// attention_84464826843938: additive-attention pooling, MI355X (gfx950)
//
// R2: fix latency-bound structure (R1: 1 wave/SIMD, Occupancy 11%).
//  K1 pack_w_k : W_w fp32 -> bf16 MFMA B-fragment order (ws, 2 MB)
//  K2 prep_p_k : p'[b,d] = prev@W2_w + W2_b + W_b  (grid 256, was 32)
//  K3 score_k  : partial scores, grid = B*2 (DIM halves), 512 thr / 8 waves,
//                2 blocks/CU -> 16 waves/CU. c never materialized.
//  K4 wsum_k   : softmax (per-block recompute) + q = sum_r aw*features,
//                grid = B*4, 4 blocks/CU, streaming.

#define B_ 256
#define R_ 64
#define F_ 2048
#define H_ 512
#define DIM_ 512

typedef short bf16x8 __attribute__((ext_vector_type(8)));
typedef float f32x4 __attribute__((ext_vector_type(4)));

__device__ __forceinline__ ushort f2bf(float x) {
  __hip_bfloat16 h = __float2bfloat16(x);
  return __builtin_bit_cast(ushort, h);
}

__device__ __forceinline__ uint4 pack8(float4 x, float4 y) {
  uint4 r;
  r.x = (uint)f2bf(x.x) | ((uint)f2bf(x.y) << 16);
  r.y = (uint)f2bf(x.z) | ((uint)f2bf(x.w) << 16);
  r.z = (uint)f2bf(y.x) | ((uint)f2bf(y.y) << 16);
  r.w = (uint)f2bf(y.z) | ((uint)f2bf(y.w) << 16);
  return r;
}

// wpack[((kt32*32 + ctg)*64 + g*16 + c)*8 + i] = bf16(W_w[kt32*32 + g*8 + i][ctg*16 + c])
__global__ void pack_w_k(const float* __restrict__ Ww, ushort* __restrict__ wpack) {
  int idx = blockIdx.x * 256 + threadIdx.x;
  float v = Ww[idx];
  int k = idx >> 9;
  int d = idx & 511;
  int kt = k >> 5, kr = k & 31;
  int g = kr >> 3, i = kr & 7;
  int ctg = d >> 4, c = d & 15;
  size_t dst = ((size_t)((kt * 32 + ctg) * 64 + g * 16 + c)) * 8 + (size_t)i;
  wpack[dst] = f2bf(v);
}

// p'[b][d] = prev[b]@W2_w[:,d] + W2_b[d] + W_b[d]; grid = 32 bgroups x 8 dslices
__global__ __launch_bounds__(256) void prep_p_k(const float* __restrict__ prev,
                                                const float* __restrict__ W2w,
                                                const float* __restrict__ W2b,
                                                const float* __restrict__ Wb,
                                                float* __restrict__ pprime) {
  __shared__ float lprev[8][H_];
  int bg = blockIdx.x >> 3;
  int d0 = (blockIdx.x & 7) * 64;
  int t = threadIdx.x;
  const float4* src = reinterpret_cast<const float4*>(prev + (size_t)bg * 8 * H_);
  float4* dst = reinterpret_cast<float4*>(&lprev[0][0]);
  for (int i = t; i < 8 * H_ / 4; i += 256) dst[i] = src[i];
  __syncthreads();
  int d = d0 + (t & 63);
  int bq = t >> 6;                       // handles batches bq and bq+4
  float a0 = 0.f, a1 = 0.f;
  #pragma unroll 8
  for (int h = 0; h < H_; ++h) {
    float wv = W2w[h * DIM_ + d];
    a0 += lprev[bq][h] * wv;
    a1 += lprev[bq + 4][h] * wv;
  }
  float bias = W2b[d] + Wb[d];
  pprime[(size_t)(bg * 8 + bq) * DIM_ + d] = a0 + bias;
  pprime[(size_t)(bg * 8 + bq + 4) * DIM_ + d] = a1 + bias;
}

__device__ __forceinline__ float fast_tanh(float x) {
  float e = __expf(2.f * x);
  return 1.f - 2.f / (e + 1.f);
}

// Partial scores: sp[b][half][r] = sum_{d in half} tanh(c[b][r][d]+p'[b][d])*W3[d]
__global__ __launch_bounds__(512, 4) void score_k(const float* __restrict__ feat,
                                                  const ushort* __restrict__ wpack,
                                                  const float* __restrict__ pprime,
                                                  const float* __restrict__ W3,
                                                  float* __restrict__ sp) {
  int b = blockIdx.x >> 1;
  int half = blockIdx.x & 1;
  int t = threadIdx.x;
  int wid = t >> 6;                       // 8 waves, each owns 32 cols
  int l = t & 63;
  int l15 = l & 15, g = l >> 4;
  int colbase = half * 256;
  int ctgbase = half * 16 + wid * 2;      // 16-col group index for this wave
  const float* featB = feat + (size_t)b * R_ * F_;

  __shared__ uint4 ldsA[2][512];          // 64 rows x 64 k bf16, double buffered
  __shared__ float lds_part[8][R_];

  f32x4 acc[4][2];
  #pragma unroll
  for (int rt = 0; rt < 4; ++rt)
    #pragma unroll
    for (int ct = 0; ct < 2; ++ct)
      acc[rt][ct] = (f32x4){0.f, 0.f, 0.f, 0.f};

  int row = t >> 3, kq = t & 7;           // staging: thread covers 8 floats of one row
  const float* rowp = featB + (size_t)row * F_ + kq * 8;

  { // prologue: stage K-tile 0
    const float4* src = reinterpret_cast<const float4*>(rowp);
    ldsA[0][kq * 64 + row] = pack8(src[0], src[1]);
  }

  for (int kt = 0; kt < 32; ++kt) {       // K-step = 64
    int cur = kt & 1;
    float4 a0, a1;
    if (kt < 31) {
      const float4* src = reinterpret_cast<const float4*>(rowp + (kt + 1) * 64);
      a0 = src[0]; a1 = src[1];
    }
    // this step's B-fragments (L2-hot, 1 KB/wave contiguous per frag)
    uint4 bfr[2][2];
    #pragma unroll
    for (int s = 0; s < 2; ++s)
      #pragma unroll
      for (int ct = 0; ct < 2; ++ct) {
        const ushort* wp = wpack + ((size_t)(kt * 2 + s) * 32 + (size_t)(ctgbase + ct)) * 512 + (size_t)l * 8;
        bfr[s][ct] = *reinterpret_cast<const uint4*>(wp);
      }

    __syncthreads();

    bf16x8 af[2][4];
    #pragma unroll
    for (int s = 0; s < 2; ++s)
      #pragma unroll
      for (int rt = 0; rt < 4; ++rt)
        af[s][rt] = __builtin_bit_cast(bf16x8, ldsA[cur][(s * 4 + g) * 64 + rt * 16 + l15]);

    #pragma unroll
    for (int s = 0; s < 2; ++s)
      #pragma unroll
      for (int ct = 0; ct < 2; ++ct) {
        bf16x8 bv = __builtin_bit_cast(bf16x8, bfr[s][ct]);
        #pragma unroll
        for (int rt = 0; rt < 4; ++rt)
          acc[rt][ct] = __builtin_amdgcn_mfma_f32_16x16x32_bf16(af[s][rt], bv, acc[rt][ct], 0, 0, 0);
      }

    if (kt < 31)
      ldsA[cur ^ 1][kq * 64 + row] = pack8(a0, a1);
  }

  // epilogue: tanh + W3 dot in registers
  // acc[rt][ct][j] = c[row = rt*16 + g*4 + j][col = colbase + wid*32 + ct*16 + l15]
  float pp[2], w3v[2];
  #pragma unroll
  for (int ct = 0; ct < 2; ++ct) {
    int col = colbase + wid * 32 + ct * 16 + l15;
    pp[ct] = pprime[b * DIM_ + col];
    w3v[ct] = W3[col];
  }
  #pragma unroll
  for (int rt = 0; rt < 4; ++rt) {
    #pragma unroll
    for (int j = 0; j < 4; ++j) {
      float v = fast_tanh(acc[rt][0][j] + pp[0]) * w3v[0]
              + fast_tanh(acc[rt][1][j] + pp[1]) * w3v[1];
      v += __shfl_xor(v, 1);
      v += __shfl_xor(v, 2);
      v += __shfl_xor(v, 4);
      v += __shfl_xor(v, 8);
      if (l15 == 0) lds_part[wid][rt * 16 + g * 4 + j] = v;
    }
  }
  __syncthreads();

  if (t < R_) {
    float s = 0.f;
    #pragma unroll
    for (int w = 0; w < 8; ++w) s += lds_part[w][t];
    sp[(size_t)(b * 2 + half) * R_ + t] = s;
  }
}

// softmax + weighted sum: grid = B*4, each block covers 512 f
__global__ __launch_bounds__(256) void wsum_k(const float* __restrict__ feat,
                                              const float* __restrict__ sp,
                                              float* __restrict__ out) {
  int b = blockIdx.x >> 2;
  int f0 = (blockIdx.x & 3) * 512;
  int t = threadIdx.x;
  __shared__ float lds_aw[R_];

  if (t < R_) {
    float s = sp[(size_t)b * 2 * R_ + t] + sp[(size_t)(b * 2 + 1) * R_ + t];
    float m = s;
    #pragma unroll
    for (int off = 32; off >= 1; off >>= 1) m = fmaxf(m, __shfl_xor(m, off));
    float e = __expf(s - m);
    float su = e;
    #pragma unroll
    for (int off = 32; off >= 1; off >>= 1) su += __shfl_xor(su, off);
    lds_aw[t] = e / su;
  }
  __syncthreads();

  const float* fp = feat + (size_t)b * R_ * F_ + f0 + t * 2;
  float qx = 0.f, qy = 0.f;
  #pragma unroll 8
  for (int r = 0; r < R_; ++r) {
    float a = lds_aw[r];
    float2 v = *reinterpret_cast<const float2*>(fp + (size_t)r * F_);
    qx += a * v.x;
    qy += a * v.y;
  }
  *reinterpret_cast<float2*>(out + (size_t)b * F_ + f0 + t * 2) = (float2){qx, qy};
}

extern "C" void kernel_launch(void* const* d_in, const int* in_sizes, int n_in,
                              void* d_out, int out_size, void* d_ws, size_t ws_size,
                              hipStream_t stream) {
  const float* feat = (const float*)d_in[0];   // [B,R,F]
  const float* prev = (const float*)d_in[1];   // [B,H]
  const float* Ww   = (const float*)d_in[2];   // [F,DIM]
  const float* Wb   = (const float*)d_in[3];   // [DIM]
  const float* W2w  = (const float*)d_in[4];   // [H,DIM]
  const float* W2b  = (const float*)d_in[5];   // [DIM]
  const float* W3w  = (const float*)d_in[6];   // [DIM,1]
  // d_in[7] = W3_b: cancels in softmax
  float* out = (float*)d_out;

  ushort* wpack  = (ushort*)d_ws;                                          // 2 MB
  float*  pprime = (float*)((char*)d_ws + (size_t)F_ * DIM_ * 2);          // 512 KB
  float*  sp     = (float*)((char*)d_ws + (size_t)F_ * DIM_ * 2
                                        + (size_t)B_ * DIM_ * 4);          // 128 KB

  pack_w_k<<<(F_ * DIM_) / 256, 256, 0, stream>>>(Ww, wpack);
  prep_p_k<<<256, 256, 0, stream>>>(prev, W2w, W2b, Wb, pprime);
  score_k<<<B_ * 2, 512, 0, stream>>>(feat, wpack, pprime, W3w, sp);
  wsum_k<<<B_ * 4, 256, 0, stream>>>(feat, sp, out);
}